// Round 1
// baseline (1733.214 us; speedup 1.0000x reference)
//
#include <hip/hip_runtime.h>

// Depthwise 3x3 conv, stride 1, VALID, fp32.
// x: (16, 64, 512, 512), w: (64, 3, 3), out: (16, 64, 510, 510)

#define NC_TOTAL 1024      // 16*64 images (n,c) pairs
#define CHN 64
#define H 512
#define W 512
#define HO 510
#define WO 510
#define TILE_H 8
#define CHUNKS 128         // 512/4 column chunks of 4 outputs each
#define BLOCKS_PER_IMG 32  // (64 rowtiles * 128 chunks) / 256 threads

__global__ __launch_bounds__(256)
void dwconv3x3_kernel(const float* __restrict__ x,
                      const float* __restrict__ w,
                      float* __restrict__ out)
{
    // Block-uniform image index -> weights become scalar loads (SGPRs).
    const int nc  = blockIdx.x >> 5;          // / BLOCKS_PER_IMG
    const int bin = blockIdx.x & 31;
    const int s   = bin * 256 + threadIdx.x;  // slot within image
    const int chunk   = s & (CHUNKS - 1);     // 0..127 (consecutive lanes -> consecutive cols)
    const int rowtile = s >> 7;               // 0..63
    const int x0 = chunk * 4;
    const int y0 = rowtile * TILE_H;

    const int c = nc & (CHN - 1);
    const float* wc = w + c * 9;
    const float w00 = wc[0], w01 = wc[1], w02 = wc[2];
    const float w10 = wc[3], w11 = wc[4], w12 = wc[5];
    const float w20 = wc[6], w21 = wc[7], w22 = wc[8];

    const float* __restrict__ xin = x + (size_t)nc * (H * W);
    float* __restrict__ op = out + (size_t)nc * ((size_t)HO * WO);

    float r0[6], r1[6], r2[6];

    // Load 6 input columns [x0, x0+5] of row y into r.
    // float4 is 16B-aligned (row stride 512, x0 % 4 == 0). Second load is a
    // float2 (8B-aligned); skipped for chunk 127 (x0=508) where it would read
    // past the row (and past the tensor on the very last row).
    auto load_row = [&](int y, float* r) {
        const float* p = xin + (size_t)y * W + x0;
        float4 a = *(const float4*)p;
        r[0] = a.x; r[1] = a.y; r[2] = a.z; r[3] = a.w;
        if (x0 + 5 < W) {
            float2 b = *(const float2*)(p + 4);
            r[4] = b.x; r[5] = b.y;
        } else {
            r[4] = 0.f; r[5] = 0.f;
        }
    };

    load_row(y0,     r0);
    load_row(y0 + 1, r1);

#pragma unroll
    for (int i = 0; i < TILE_H; ++i) {
        const int y = y0 + i;
        if (y >= HO) break;            // bottom tile: rows 504..509 only
        load_row(y + 2, r2);

        float o0 = r0[0]*w00 + r0[1]*w01 + r0[2]*w02
                 + r1[0]*w10 + r1[1]*w11 + r1[2]*w12
                 + r2[0]*w20 + r2[1]*w21 + r2[2]*w22;
        float o1 = r0[1]*w00 + r0[2]*w01 + r0[3]*w02
                 + r1[1]*w10 + r1[2]*w11 + r1[3]*w12
                 + r2[1]*w20 + r2[2]*w21 + r2[3]*w22;
        float o2 = r0[2]*w00 + r0[3]*w01 + r0[4]*w02
                 + r1[2]*w10 + r1[3]*w11 + r1[4]*w12
                 + r2[2]*w20 + r2[3]*w21 + r2[4]*w22;
        float o3 = r0[3]*w00 + r0[4]*w01 + r0[5]*w02
                 + r1[3]*w10 + r1[4]*w11 + r1[5]*w12
                 + r2[3]*w20 + r2[4]*w21 + r2[5]*w22;

        float* orow = op + (size_t)y * WO + x0;
        // (nc*510 + y)*510 + x0 is always even -> 8B-aligned float2 stores.
        *(float2*)orow = make_float2(o0, o1);
        if (x0 + 3 < WO) {             // chunk 127 has only 2 valid outputs
            *(float2*)(orow + 2) = make_float2(o2, o3);
        }

#pragma unroll
        for (int k = 0; k < 6; ++k) { r0[k] = r1[k]; r1[k] = r2[k]; }
    }
}

extern "C" void kernel_launch(void* const* d_in, const int* in_sizes, int n_in,
                              void* d_out, int out_size, void* d_ws, size_t ws_size,
                              hipStream_t stream)
{
    const float* x = (const float*)d_in[0];
    const float* w = (const float*)d_in[1];
    float* out = (float*)d_out;

    dim3 grid(NC_TOTAL * BLOCKS_PER_IMG);  // 32768 blocks
    dim3 block(256);
    dwconv3x3_kernel<<<grid, block, 0, stream>>>(x, w, out);
}